// Round 10
// baseline (393.583 us; speedup 1.0000x reference)
//
#include <hip/hip_runtime.h>
#include <hip/hip_bf16.h>

#define B_SZ   1024
#define T_SZ   64
#define D_IN   1662
#define D_INP  1664                 // padded to 32-multiple
#define M_SZ   (B_SZ * T_SZ)        // 65536

typedef __attribute__((ext_vector_type(8))) short short8;
typedef __attribute__((ext_vector_type(4))) float f32x4;
typedef unsigned short ushort_t;

// fp32 -> bf16 round-to-nearest-even (finite inputs)
__device__ __forceinline__ unsigned short f2bf(float f) {
    unsigned u = __builtin_bit_cast(unsigned, f);
    u += 0x7FFFu + ((u >> 16) & 1u);
    return (unsigned short)(u >> 16);
}
__device__ __forceinline__ float bf2f(ushort_t u) {
    return __builtin_bit_cast(float, (unsigned)u << 16);
}

// async global->LDS, 16B per lane, dest = wave-uniform base + lane*16
#define GLD16(gp, lp) __builtin_amdgcn_global_load_lds(                        \
    (const __attribute__((address_space(1))) void*)(gp),                       \
    (__attribute__((address_space(3))) void*)(lp), 16, 0, 0)

__device__ __forceinline__ float sigmoid_f(float x) {
    return 1.0f / (1.0f + __expf(-x));
}
__device__ __forceinline__ float tanh_f(float x) {
    float a = fabsf(x);
    float e = __expf(2.0f * a);
    float r = 1.0f - 2.0f / (e + 1.0f);
    return copysignf(r, x);
}

// ---------------------------------------------------------------------------
// convert fp32 [256,1662] -> bf16 [256,1664] (w_ih1 only)
// ---------------------------------------------------------------------------
__global__ __launch_bounds__(256) void convert_w1(
    const float* __restrict__ src, ushort_t* __restrict__ dst)
{
    constexpr int cpr = D_INP >> 3;
    const int total = 256 * cpr;
    const int stride = gridDim.x * blockDim.x;
    for (int idx = blockIdx.x * blockDim.x + threadIdx.x;
         idx < total; idx += stride) {
        const int row  = idx / cpr;
        const int base = (idx % cpr) << 3;
        const float* s = src + (size_t)row * D_IN;
        short8 o;
        #pragma unroll
        for (int j = 0; j < 4; ++j) {
            const int k = base + 2 * j;
            float2 v = make_float2(0.f, 0.f);
            if (k < D_IN) v = *(const float2*)(s + k);
            o[2 * j]     = (short)f2bf(v.x);
            o[2 * j + 1] = (short)f2bf(v.y);
        }
        *(short8*)(dst + (size_t)row * D_INP + base) = o;
    }
}

// ---------------------------------------------------------------------------
// Layer-1 GEMM, counted-vmcnt pipeline (T3/T4-lite):
// out[M,256]bf16 = A[M,K]fp32 @ W[256,Kp]bf16^T.
// 64x256 tile, BK=32, 256 threads (4 waves), 3 blocks/CU.
// A: 2-deep register prefetch (ping-pong reg sets, macro-static), pack->LDS.
// W: per-wave self-staged GLD16 into double-buffered LDS (each wave reads
//    only its own staged rows -> own vmcnt suffices; no cross-wave hazard).
// ONE raw s_barrier per iter (As visibility), lgkmcnt(0) before it,
// s_waitcnt vmcnt(4) at iter end (A(t+2) stays in flight; never 0 mid-loop).
// Tail: A loads address-clamped (garbage cols x W zero-pad = 0).
// ---------------------------------------------------------------------------
__global__ __launch_bounds__(256, 3) void gemm_l1(
    const float* __restrict__ A, const ushort_t* __restrict__ W,
    ushort_t* __restrict__ out)
{
    constexpr int K = D_IN, Kp = D_INP, G = 256;
    constexpr int NIT = 52;                       // ceil(K/32)
    __shared__ __align__(16) ushort_t As[2][64 * 32];    //  8 KB
    __shared__ __align__(16) ushort_t Ws[2][256 * 32];   // 32 KB

    const int tid = threadIdx.x, lane = tid & 63, wid = tid >> 6;
    const int m0 = blockIdx.x * 64;

    // A: row tid>>2 (0..63), 8 fp32 at col (tid&3)*8
    const int arow  = tid >> 2;
    const int acolb = (tid & 3) * 8;
    const float* Abase = A + (size_t)(m0 + arow) * K + acolb;
    const int kmax = K - 2 - acolb;               // clamp: always in-bounds

    // W: wave wid stages rows wid*64..+63 in 4 GLD16 chunks of 16 rows
    const size_t wlofs = (size_t)(lane >> 2) * Kp + (lane & 3) * 8;
    const ushort_t* WgBase = W + (size_t)(wid * 64) * Kp + wlofs;

    const int fr = lane & 15, kq = (lane >> 4) * 8;

    f32x4 acc[4][4] = {};
    float2 av0[4], av1[4];                        // ping-pong A prefetch

    // --- prologue: A(0)->av0, W(0)->Ws[0], A(1)->av1 (newest) ---
    #pragma unroll
    for (int j = 0; j < 4; ++j)
        av0[j] = *(const float2*)(Abase + 2 * j);
    __builtin_amdgcn_sched_barrier(0);
    #pragma unroll
    for (int c = 0; c < 4; ++c)
        GLD16(WgBase + (size_t)(c * 16) * Kp,
              &Ws[0][(wid * 64 + c * 16) * 32]);
    __builtin_amdgcn_sched_barrier(0);
    #pragma unroll
    for (int j = 0; j < 4; ++j)
        av1[j] = *(const float2*)(Abase + min(32 + 2 * j, kmax));
    __builtin_amdgcn_sched_barrier(0);
    asm volatile("s_waitcnt vmcnt(4)" ::: "memory");   // A(0)+W(0) done

#define L1_ITER(T, AV)                                                         \
  do {                                                                         \
    const int bcur = (T) & 1;                                                  \
    short8 pk;                                                                 \
    _Pragma("unroll")                                                          \
    for (int j = 0; j < 4; ++j) {                                              \
        pk[2 * j]     = (short)f2bf(AV[j].x);                                  \
        pk[2 * j + 1] = (short)f2bf(AV[j].y);                                  \
    }                                                                          \
    *(short8*)&As[bcur][arow * 32 + acolb] = pk;                               \
    asm volatile("s_waitcnt lgkmcnt(0)" ::: "memory");                         \
    __builtin_amdgcn_s_barrier();                                              \
    __builtin_amdgcn_sched_barrier(0);                                         \
    if ((T) + 1 < NIT) {                                                       \
        const size_t kw = (size_t)((T) + 1) * 32;                              \
        _Pragma("unroll")                                                      \
        for (int c = 0; c < 4; ++c)                                            \
            GLD16(WgBase + (size_t)(c * 16) * Kp + kw,                         \
                  &Ws[((T) + 1) & 1][(wid * 64 + c * 16) * 32]);               \
    }                                                                          \
    __builtin_amdgcn_sched_barrier(0);                                         \
    if ((T) + 2 < NIT) {                                                       \
        const int kA = ((T) + 2) * 32;                                         \
        _Pragma("unroll")                                                      \
        for (int j = 0; j < 4; ++j)                                            \
            AV[j] = *(const float2*)(Abase + min(kA + 2 * j, kmax));           \
    }                                                                          \
    __builtin_amdgcn_sched_barrier(0);                                         \
    {                                                                          \
        short8 af[4], bfr[4];                                                  \
        _Pragma("unroll")                                                      \
        for (int fm = 0; fm < 4; ++fm)                                         \
            af[fm] = *(const short8*)&As[bcur][(fm * 16 + fr) * 32 + kq];      \
        _Pragma("unroll")                                                      \
        for (int fn = 0; fn < 4; ++fn)                                         \
            bfr[fn] = *(const short8*)                                         \
                &Ws[bcur][(wid * 64 + fn * 16 + fr) * 32 + kq];                \
        _Pragma("unroll")                                                      \
        for (int fm = 0; fm < 4; ++fm)                                         \
            _Pragma("unroll")                                                  \
            for (int fn = 0; fn < 4; ++fn)                                     \
                acc[fm][fn] = __builtin_amdgcn_mfma_f32_16x16x32_bf16(         \
                    af[fm], bfr[fn], acc[fm][fn], 0, 0, 0);                    \
    }                                                                          \
    __builtin_amdgcn_sched_barrier(0);                                         \
    if ((T) < NIT - 2) asm volatile("s_waitcnt vmcnt(4)" ::: "memory");        \
    else               asm volatile("s_waitcnt vmcnt(0)" ::: "memory");        \
  } while (0)

    for (int tt = 0; tt < NIT / 2; ++tt) {
        L1_ITER(2 * tt,     av0);
        L1_ITER(2 * tt + 1, av1);
    }
#undef L1_ITER

    // epilogue: bf16, no bias. C/D: col=lane&15, row=(lane>>4)*4+j
    const int rbase = (lane >> 4) * 4;
    #pragma unroll
    for (int fn = 0; fn < 4; ++fn) {
        const int g = wid * 64 + fn * 16 + fr;
        #pragma unroll
        for (int fm = 0; fm < 4; ++fm) {
            const int mbase = m0 + fm * 16 + rbase;
            #pragma unroll
            for (int j = 0; j < 4; ++j)
                out[(size_t)(mbase + j) * G + g] = f2bf(acc[fm][fn][j]);
        }
    }
}

// ---------------------------------------------------------------------------
// Pipelined 3-layer LSTM. 256 blocks x 512 threads; 4 batch rows/block.
// Wave roles: wid 0-1 -> layer1 (H=64), 2-5 -> layer2 (H=128), 6-7 -> layer3.
// ---------------------------------------------------------------------------
__global__ __launch_bounds__(512, 1) void lstm3_pipe(
    const ushort_t* __restrict__ xg1,   // [B,T,256] bf16 (no bias)
    const float* __restrict__ whh1,
    const float* __restrict__ bih1, const float* __restrict__ bhh1,
    const float* __restrict__ wih2, const float* __restrict__ whh2,
    const float* __restrict__ bih2, const float* __restrict__ bhh2,
    const float* __restrict__ wih3, const float* __restrict__ whh3,
    const float* __restrict__ bih3, const float* __restrict__ bhh3,
    float* __restrict__ hlast, int Tn)  // [B,64]
{
    __shared__ ushort_t h1sh[2][16 * 64];
    __shared__ ushort_t h2sh[2][16 * 128];
    __shared__ ushort_t h3sh[2][16 * 64];
    __shared__ ushort_t xsh[2][4 * 256];
    __shared__ float    gsh[4][1024];    // gates, col = sec + g*Hl + u
    __shared__ float    bsh[1024];       // bias table, same col layout

    const int tid = threadIdx.x, lane = tid & 63, wid = tid >> 6;
    const int r0 = blockIdx.x * 4;
    const int fr = lane & 15, hi = lane >> 4, kq = hi * 8;

    int role, uw;
    if (wid < 2)      { role = 1; uw = wid * 32; }
    else if (wid < 6) { role = 2; uw = (wid - 2) * 32; }
    else              { role = 3; uw = (wid - 6) * 32; }

    short8 bregB[2][4][2];
    short8 bregA[2][4][4];
    #pragma unroll
    for (int ut = 0; ut < 2; ++ut)
        #pragma unroll
        for (int g = 0; g < 4; ++g) {
            const int uu = uw + ut * 16 + fr;
            const float *pB, *pA = nullptr;
            if (role == 1)      { pB = whh1 + (size_t)(g * 64 + uu) * 64; }
            else if (role == 2) { pB = wih2 + (size_t)(g * 128 + uu) * 64;
                                  pA = whh2 + (size_t)(g * 128 + uu) * 128; }
            else                { pB = whh3 + (size_t)(g * 64 + uu) * 64;
                                  pA = wih3 + (size_t)(g * 64 + uu) * 128; }
            #pragma unroll
            for (int ks = 0; ks < 2; ++ks) {
                short8 b;
                #pragma unroll
                for (int j = 0; j < 8; ++j)
                    b[j] = (short)f2bf(pB[ks * 32 + kq + j]);
                bregB[ut][g][ks] = b;
            }
            if (role >= 2) {
                #pragma unroll
                for (int ks = 0; ks < 4; ++ks) {
                    short8 b;
                    #pragma unroll
                    for (int j = 0; j < 8; ++j)
                        b[j] = (short)f2bf(pA[ks * 32 + kq + j]);
                    bregA[ut][g][ks] = b;
                }
            }
        }

    for (int i = tid; i < 1024; i += 512) {
        float bv;
        if (i < 256)      bv = bih1[i] + bhh1[i];
        else if (i < 768) bv = bih2[i - 256] + bhh2[i - 256];
        else              bv = bih3[i - 768] + bhh3[i - 768];
        bsh[i] = bv;
        h1sh[0][i] = 0; h1sh[1][i] = 0;
        h3sh[0][i] = 0; h3sh[1][i] = 0;
    }
    for (int i = tid; i < 2048; i += 512) { h2sh[0][i] = 0; h2sh[1][i] = 0; }

    if (tid < 128) {
        const int rw = tid >> 5, xc = (tid & 31) * 8;
        *(short8*)&xsh[0][rw * 256 + xc] =
            *(const short8*)(xg1 + ((size_t)(r0 + rw) * Tn) * 256 + xc);
    }

    float c[2] = {0.f, 0.f};
    __syncthreads();

    const int nSteps = Tn + 2;            // 66
    for (int s = 0; s < nSteps; ++s) {
        const int rb = s & 1, wb = rb ^ 1;

        short8 xr;
        const bool doX = (tid < 128) && (s + 1 < Tn);
        if (doX) {
            const int rw = tid >> 5, xc = (tid & 31) * 8;
            xr = *(const short8*)(xg1 +
                 ((size_t)(r0 + rw) * Tn + (s + 1)) * 256 + xc);
        }

        const bool act = (role == 1) ? (s < Tn)
                       : (role == 2) ? (s >= 1 && s <= Tn)
                                     : (s >= 2 && s <= Tn + 1);
        if (act) {
            short8 a2r[2], a4r[4];
            const ushort_t* src2 = (role == 3) ? h3sh[rb] : h1sh[rb];
            #pragma unroll
            for (int ks = 0; ks < 2; ++ks) {
                const int k0 = ks * 32 + kq;
                a2r[ks] = *(const short8*)&src2[fr * 64 + (k0 ^ ((fr & 7) << 3))];
            }
            if (role >= 2) {
                #pragma unroll
                for (int ks = 0; ks < 4; ++ks) {
                    const int k0 = ks * 32 + kq;
                    a4r[ks] = *(const short8*)
                        &h2sh[rb][fr * 128 + (k0 ^ ((fr & 7) << 3))];
                }
            }
            const int sec = (role == 1) ? 0 : (role == 2) ? 256 : 768;
            const int Hl  = (role == 2) ? 128 : 64;
            #pragma unroll
            for (int ut = 0; ut < 2; ++ut)
                #pragma unroll
                for (int g = 0; g < 4; ++g) {
                    f32x4 acc = {};
                    #pragma unroll
                    for (int ks = 0; ks < 2; ++ks)
                        acc = __builtin_amdgcn_mfma_f32_16x16x32_bf16(
                            a2r[ks], bregB[ut][g][ks], acc, 0, 0, 0);
                    if (role >= 2) {
                        #pragma unroll
                        for (int ks = 0; ks < 4; ++ks)
                            acc = __builtin_amdgcn_mfma_f32_16x16x32_bf16(
                                a4r[ks], bregA[ut][g][ks], acc, 0, 0, 0);
                    }
                    if (hi == 0) {      // rows 0-3 are the real batch rows
                        const int col = sec + g * Hl + uw + ut * 16 + fr;
                        #pragma unroll
                        for (int j = 0; j < 4; ++j)
                            gsh[j][col] = acc[j];
                    }
                }
        }
        __syncthreads();                 // gates visible

        #pragma unroll
        for (int i = 0; i < 2; ++i) {
            const int item = tid + i * 512;
            const int row = item >> 8, ug = item & 255;
            int u, Hl, sec, tt, lay;
            if (ug < 64)       { lay = 1; u = ug;       Hl = 64;  sec = 0;   tt = s; }
            else if (ug < 192) { lay = 2; u = ug - 64;  Hl = 128; sec = 256; tt = s - 1; }
            else               { lay = 3; u = ug - 192; Hl = 64;  sec = 768; tt = s - 2; }
            if (tt >= 0 && tt < Tn) {
                const int col0 = sec + u;
                float gi = gsh[row][col0]          + bsh[col0];
                float gf = gsh[row][col0 + Hl]     + bsh[col0 + Hl];
                float gg = gsh[row][col0 + 2 * Hl] + bsh[col0 + 2 * Hl];
                float go = gsh[row][col0 + 3 * Hl] + bsh[col0 + 3 * Hl];
                if (lay == 1) {
                    const ushort_t* xb = &xsh[s & 1][row * 256 + u];
                    gi += bf2f(xb[0]);   gf += bf2f(xb[64]);
                    gg += bf2f(xb[128]); go += bf2f(xb[192]);
                }
                const float iv = sigmoid_f(gi);
                const float fv = sigmoid_f(gf);
                const float gv = tanh_f(gg);
                const float ov = sigmoid_f(go);
                c[i] = fmaf(fv, c[i], iv * gv);
                const float h = ov * tanh_f(c[i]);
                ushort_t* hdst = (lay == 1) ? h1sh[wb]
                               : (lay == 2) ? h2sh[wb] : h3sh[wb];
                hdst[row * Hl + (u ^ (row << 3))] = f2bf(h);   // row<4
                if (lay == 3 && tt == Tn - 1)
                    hlast[(size_t)(r0 + row) * 64 + u] = h;
            }
        }

        if (doX) {
            const int rw = tid >> 5, xc = (tid & 31) * 8;
            *(short8*)&xsh[(s + 1) & 1][rw * 256 + xc] = xr;
        }
        __syncthreads();                 // h(wb), xg(s+1) visible
    }
}

// ---------------------------------------------------------------------------
// FC head: hlast[B,64] -> fc1 relu -> fc2 relu -> fc3 -> softmax
// ---------------------------------------------------------------------------
__global__ __launch_bounds__(256) void head_kernel(
    const float* __restrict__ hlast,
    const float* __restrict__ w1, const float* __restrict__ b1,
    const float* __restrict__ w2, const float* __restrict__ b2,
    const float* __restrict__ w3, const float* __restrict__ b3,
    float* __restrict__ out)
{
    __shared__ float W1[64][64];
    __shared__ float W2[32][64];
    __shared__ float W3[3][32];
    __shared__ float hin[16][64];
    __shared__ float a1[16][64];
    __shared__ float a2[16][32];
    __shared__ float lg[16][3];

    const int tid = threadIdx.x;
    const int r0 = blockIdx.x * 16;

    for (int i = tid; i < 64 * 64; i += 256) W1[i >> 6][i & 63] = w1[i];
    for (int i = tid; i < 32 * 64; i += 256) W2[i >> 6][i & 63] = w2[i];
    for (int i = tid; i < 3 * 32; i += 256) W3[i >> 5][i & 31] = w3[i];
    for (int i = tid; i < 16 * 64; i += 256) {
        int r = i >> 6, u = i & 63;
        hin[r][u] = hlast[(size_t)(r0 + r) * 64 + u];
    }
    __syncthreads();

    for (int i = tid; i < 16 * 64; i += 256) {
        int r = i >> 6, j = i & 63;
        float s = b1[j];
        #pragma unroll
        for (int k = 0; k < 64; ++k) s = fmaf(hin[r][k], W1[j][k], s);
        a1[r][j] = fmaxf(s, 0.f);
    }
    __syncthreads();

    for (int i = tid; i < 16 * 32; i += 256) {
        int r = i >> 5, j = i & 31;
        float s = b2[j];
        #pragma unroll
        for (int k = 0; k < 64; ++k) s = fmaf(a1[r][k], W2[j][k], s);
        a2[r][j] = fmaxf(s, 0.f);
    }
    __syncthreads();

    for (int i = tid; i < 16 * 3; i += 256) {
        int r = i / 3, j = i % 3;
        float s = b3[j];
        #pragma unroll
        for (int k = 0; k < 32; ++k) s = fmaf(a2[r][k], W3[j][k], s);
        lg[r][j] = s;
    }
    __syncthreads();

    if (tid < 16) {
        float l0 = lg[tid][0], l1 = lg[tid][1], l2 = lg[tid][2];
        float m = fmaxf(l0, fmaxf(l1, l2));
        float e0 = __expf(l0 - m), e1 = __expf(l1 - m), e2 = __expf(l2 - m);
        float inv = 1.0f / (e0 + e1 + e2);
        out[(size_t)(r0 + tid) * 3 + 0] = e0 * inv;
        out[(size_t)(r0 + tid) * 3 + 1] = e1 * inv;
        out[(size_t)(r0 + tid) * 3 + 2] = e2 * inv;
    }
}

// ---------------------------------------------------------------------------
extern "C" void kernel_launch(void* const* d_in, const int* in_sizes, int n_in,
                              void* d_out, int out_size, void* d_ws, size_t ws_size,
                              hipStream_t stream)
{
    const float* x    = (const float*)d_in[0];
    const float* wih1 = (const float*)d_in[1];
    const float* whh1 = (const float*)d_in[2];
    const float* bih1 = (const float*)d_in[3];
    const float* bhh1 = (const float*)d_in[4];
    const float* wih2 = (const float*)d_in[5];
    const float* whh2 = (const float*)d_in[6];
    const float* bih2 = (const float*)d_in[7];
    const float* bhh2 = (const float*)d_in[8];
    const float* wih3 = (const float*)d_in[9];
    const float* whh3 = (const float*)d_in[10];
    const float* bih3 = (const float*)d_in[11];
    const float* bhh3 = (const float*)d_in[12];
    const float* f1w  = (const float*)d_in[13];
    const float* f1b  = (const float*)d_in[14];
    const float* f2w  = (const float*)d_in[15];
    const float* f2b  = (const float*)d_in[16];
    const float* f3w  = (const float*)d_in[17];
    const float* f3b  = (const float*)d_in[18];
    float* outp = (float*)d_out;

    // workspace layout (~35 MB):
    //   bufA : 33,554,432 B  (bf16 [M,256]: xg1)
    //   hlast:    262,144 B  (fp32 [B,64])
    //   w1b  : bf16 w_ih1 (~0.9 MB)
    char* wsb = (char*)d_ws;
    size_t off = 0;
    ushort_t* bufA  = (ushort_t*)(wsb + off); off += 33554432;
    float*    hlast = (float*)(wsb + off);    off += 262144;
    ushort_t* w1b   = (ushort_t*)(wsb + off);

    const int T = T_SZ;

    convert_w1<<<208, 256, 0, stream>>>(wih1, w1b);

    // Layer 1 input GEMM (counted-vmcnt pipeline; 3 blocks/CU)
    gemm_l1<<<M_SZ / 64, 256, 0, stream>>>(x, w1b, bufA);

    // All three LSTM layers, pipelined, one dispatch (256 blocks = all CUs)
    lstm3_pipe<<<B_SZ / 4, 512, 0, stream>>>(
        bufA, whh1, bih1, bhh1,
        wih2, whh2, bih2, bhh2,
        wih3, whh3, bih3, bhh3,
        hlast, T);

    // Head
    head_kernel<<<B_SZ / 16, 256, 0, stream>>>(
        hlast, f1w, f1b, f2w, f2b, f3w, f3b, outp);
}

// Round 11
// 371.726 us; speedup vs baseline: 1.0588x; 1.0588x over previous
//
#include <hip/hip_runtime.h>
#include <hip/hip_bf16.h>

#define B_SZ   1024
#define T_SZ   64
#define D_IN   1662
#define D_INP  1664                 // padded to 32-multiple
#define M_SZ   (B_SZ * T_SZ)        // 65536

typedef __attribute__((ext_vector_type(8))) short short8;
typedef __attribute__((ext_vector_type(4))) float f32x4;
typedef unsigned short ushort_t;

// fp32 -> bf16 round-to-nearest-even (finite inputs)
__device__ __forceinline__ unsigned short f2bf(float f) {
    unsigned u = __builtin_bit_cast(unsigned, f);
    u += 0x7FFFu + ((u >> 16) & 1u);
    return (unsigned short)(u >> 16);
}
__device__ __forceinline__ float bf2f(ushort_t u) {
    return __builtin_bit_cast(float, (unsigned)u << 16);
}

// async global->LDS, 16B per lane, dest = wave-uniform base + lane*16
#define GLD16(gp, lp) __builtin_amdgcn_global_load_lds(                        \
    (const __attribute__((address_space(1))) void*)(gp),                       \
    (__attribute__((address_space(3))) void*)(lp), 16, 0, 0)

__device__ __forceinline__ float sigmoid_f(float x) {
    return 1.0f / (1.0f + __expf(-x));
}
__device__ __forceinline__ float tanh_f(float x) {
    float a = fabsf(x);
    float e = __expf(2.0f * a);
    float r = 1.0f - 2.0f / (e + 1.0f);
    return copysignf(r, x);
}

// ---------------------------------------------------------------------------
// convert fp32 [256,1662] -> bf16 [256,1664] (w_ih1 only)
// ---------------------------------------------------------------------------
__global__ __launch_bounds__(256) void convert_w1(
    const float* __restrict__ src, ushort_t* __restrict__ dst)
{
    constexpr int cpr = D_INP >> 3;
    const int total = 256 * cpr;
    const int stride = gridDim.x * blockDim.x;
    for (int idx = blockIdx.x * blockDim.x + threadIdx.x;
         idx < total; idx += stride) {
        const int row  = idx / cpr;
        const int base = (idx % cpr) << 3;
        const float* s = src + (size_t)row * D_IN;
        short8 o;
        #pragma unroll
        for (int j = 0; j < 4; ++j) {
            const int k = base + 2 * j;
            float2 v = make_float2(0.f, 0.f);
            if (k < D_IN) v = *(const float2*)(s + k);
            o[2 * j]     = (short)f2bf(v.x);
            o[2 * j + 1] = (short)f2bf(v.y);
        }
        *(short8*)(dst + (size_t)row * D_INP + base) = o;
    }
}

// ---------------------------------------------------------------------------
// Layer-1 GEMM (r9 version — simple, compiler-scheduled):
// out[M,256]bf16 = A[M,K]fp32 @ W[256,Kp]bf16^T.
// 64x256 tile, BK=32, 256 threads (4 waves), grid M/64=1024 -> 4 blocks/CU.
// ---------------------------------------------------------------------------
__global__ __launch_bounds__(256, 4) void gemm_l1(
    const float* __restrict__ A, const ushort_t* __restrict__ W,
    ushort_t* __restrict__ out)
{
    constexpr int K = D_IN, Kp = D_INP, G = 256;
    __shared__ __align__(16) ushort_t As[64 * 32];     //  4 KB
    __shared__ __align__(16) ushort_t Ws[256 * 32];    // 16 KB

    const int tid = threadIdx.x, lane = tid & 63, wid = tid >> 6;
    const int m0 = blockIdx.x * 64;

    const int arow  = tid >> 2;
    const int acolb = (tid & 3) * 8;
    const float* Abase = A + (size_t)(m0 + arow) * K + acolb;

    const size_t wlofs = (size_t)(lane >> 2) * Kp + (lane & 3) * 8;
    const ushort_t* Wg0 = W + (size_t)(wid * 64) * Kp + wlofs;
    const ushort_t* Wg1 = Wg0 + (size_t)16 * Kp;
    const ushort_t* Wg2 = Wg0 + (size_t)32 * Kp;
    const ushort_t* Wg3 = Wg0 + (size_t)48 * Kp;
    ushort_t* lw0 = &Ws[(wid * 64) * 32];
    ushort_t* lw1 = lw0 + 16 * 32;
    ushort_t* lw2 = lw0 + 32 * 32;
    ushort_t* lw3 = lw0 + 48 * 32;

    const int fr = lane & 15, kq = (lane >> 4) * 8;

    f32x4 acc[4][4] = {};
    const int nFull = K / 32;                 // 51 full iters + 1 tail

    float2 av[4];
    #pragma unroll
    for (int j = 0; j < 4; ++j) av[j] = *(const float2*)(Abase + 2 * j);

    for (int it = 0; it <= nFull; ++it) {
        const int k0 = it * 32;
        __syncthreads();
        GLD16(Wg0 + k0, lw0); GLD16(Wg1 + k0, lw1);
        GLD16(Wg2 + k0, lw2); GLD16(Wg3 + k0, lw3);
        short8 pk;
        #pragma unroll
        for (int j = 0; j < 4; ++j) {
            pk[2 * j]     = (short)f2bf(av[j].x);
            pk[2 * j + 1] = (short)f2bf(av[j].y);
        }
        *(short8*)&As[arow * 32 + acolb] = pk;
        __syncthreads();

        if (it < nFull) {
            const int kn = (it + 1) * 32;
            if (it + 1 < nFull) {
                #pragma unroll
                for (int j = 0; j < 4; ++j)
                    av[j] = *(const float2*)(Abase + kn + 2 * j);
            } else {
                #pragma unroll
                for (int j = 0; j < 4; ++j) {
                    const int kk = kn + acolb + 2 * j;
                    av[j] = (kk < K) ? *(const float2*)(Abase + kn + 2 * j)
                                     : make_float2(0.f, 0.f);
                }
            }
        }

        short8 af[4], bfr[4];
        #pragma unroll
        for (int fm = 0; fm < 4; ++fm)
            af[fm] = *(const short8*)&As[(fm * 16 + fr) * 32 + kq];
        #pragma unroll
        for (int fn = 0; fn < 4; ++fn)
            bfr[fn] = *(const short8*)&Ws[(wid * 64 + fn * 16 + fr) * 32 + kq];
        #pragma unroll
        for (int fm = 0; fm < 4; ++fm)
            #pragma unroll
            for (int fn = 0; fn < 4; ++fn)
                acc[fm][fn] = __builtin_amdgcn_mfma_f32_16x16x32_bf16(
                    af[fm], bfr[fn], acc[fm][fn], 0, 0, 0);
    }

    const int rbase = (lane >> 4) * 4;
    #pragma unroll
    for (int fn = 0; fn < 4; ++fn) {
        const int g = wid * 64 + fn * 16 + fr;
        #pragma unroll
        for (int fm = 0; fm < 4; ++fm) {
            const int mbase = m0 + fm * 16 + rbase;
            #pragma unroll
            for (int j = 0; j < 4; ++j)
                out[(size_t)(mbase + j) * G + g] = f2bf(acc[fm][fn][j]);
        }
    }
}

// ---------------------------------------------------------------------------
// Pipelined 3-layer LSTM. 256 blocks x 512 threads; 4 batch rows/block.
// Wave roles: wid 0-1 -> layer1 (H=64), 2-5 -> layer2 (H=128), 6-7 -> layer3.
// __launch_bounds__(512,1): grid=256 means 1 block/CU regardless; no VGPR
// cap -> weight fragments (bregA+bregB ~192 VGPR) stay in registers.
// ---------------------------------------------------------------------------
__global__ __launch_bounds__(512, 1) void lstm3_pipe(
    const ushort_t* __restrict__ xg1,   // [B,T,256] bf16 (no bias)
    const float* __restrict__ whh1,
    const float* __restrict__ bih1, const float* __restrict__ bhh1,
    const float* __restrict__ wih2, const float* __restrict__ whh2,
    const float* __restrict__ bih2, const float* __restrict__ bhh2,
    const float* __restrict__ wih3, const float* __restrict__ whh3,
    const float* __restrict__ bih3, const float* __restrict__ bhh3,
    float* __restrict__ hlast, int Tn)  // [B,64]
{
    __shared__ ushort_t h1sh[2][16 * 64];
    __shared__ ushort_t h2sh[2][16 * 128];
    __shared__ ushort_t h3sh[2][16 * 64];
    __shared__ ushort_t xsh[2][4 * 256];
    __shared__ float    gsh[4][1024];    // gates, col = sec + g*Hl + u
    __shared__ float    bsh[1024];       // bias table, same col layout

    const int tid = threadIdx.x, lane = tid & 63, wid = tid >> 6;
    const int r0 = blockIdx.x * 4;
    const int fr = lane & 15, hi = lane >> 4, kq = hi * 8;

    int role, uw;
    if (wid < 2)      { role = 1; uw = wid * 32; }
    else if (wid < 6) { role = 2; uw = (wid - 2) * 32; }
    else              { role = 3; uw = (wid - 6) * 32; }

    short8 bregB[2][4][2];
    short8 bregA[2][4][4];
    #pragma unroll
    for (int ut = 0; ut < 2; ++ut)
        #pragma unroll
        for (int g = 0; g < 4; ++g) {
            const int uu = uw + ut * 16 + fr;
            const float *pB, *pA = nullptr;
            if (role == 1)      { pB = whh1 + (size_t)(g * 64 + uu) * 64; }
            else if (role == 2) { pB = wih2 + (size_t)(g * 128 + uu) * 64;
                                  pA = whh2 + (size_t)(g * 128 + uu) * 128; }
            else                { pB = whh3 + (size_t)(g * 64 + uu) * 64;
                                  pA = wih3 + (size_t)(g * 64 + uu) * 128; }
            #pragma unroll
            for (int ks = 0; ks < 2; ++ks) {
                short8 b;
                #pragma unroll
                for (int j = 0; j < 8; ++j)
                    b[j] = (short)f2bf(pB[ks * 32 + kq + j]);
                bregB[ut][g][ks] = b;
            }
            if (role >= 2) {
                #pragma unroll
                for (int ks = 0; ks < 4; ++ks) {
                    short8 b;
                    #pragma unroll
                    for (int j = 0; j < 8; ++j)
                        b[j] = (short)f2bf(pA[ks * 32 + kq + j]);
                    bregA[ut][g][ks] = b;
                }
            }
        }

    for (int i = tid; i < 1024; i += 512) {
        float bv;
        if (i < 256)      bv = bih1[i] + bhh1[i];
        else if (i < 768) bv = bih2[i - 256] + bhh2[i - 256];
        else              bv = bih3[i - 768] + bhh3[i - 768];
        bsh[i] = bv;
        h1sh[0][i] = 0; h1sh[1][i] = 0;
        h3sh[0][i] = 0; h3sh[1][i] = 0;
    }
    for (int i = tid; i < 2048; i += 512) { h2sh[0][i] = 0; h2sh[1][i] = 0; }

    if (tid < 128) {
        const int rw = tid >> 5, xc = (tid & 31) * 8;
        *(short8*)&xsh[0][rw * 256 + xc] =
            *(const short8*)(xg1 + ((size_t)(r0 + rw) * Tn) * 256 + xc);
    }

    float c[2] = {0.f, 0.f};
    __syncthreads();

    const int nSteps = Tn + 2;            // 66
    for (int s = 0; s < nSteps; ++s) {
        const int rb = s & 1, wb = rb ^ 1;

        short8 xr;
        const bool doX = (tid < 128) && (s + 1 < Tn);
        if (doX) {
            const int rw = tid >> 5, xc = (tid & 31) * 8;
            xr = *(const short8*)(xg1 +
                 ((size_t)(r0 + rw) * Tn + (s + 1)) * 256 + xc);
        }

        const bool act = (role == 1) ? (s < Tn)
                       : (role == 2) ? (s >= 1 && s <= Tn)
                                     : (s >= 2 && s <= Tn + 1);
        if (act) {
            short8 a2r[2], a4r[4];
            const ushort_t* src2 = (role == 3) ? h3sh[rb] : h1sh[rb];
            #pragma unroll
            for (int ks = 0; ks < 2; ++ks) {
                const int k0 = ks * 32 + kq;
                a2r[ks] = *(const short8*)&src2[fr * 64 + (k0 ^ ((fr & 7) << 3))];
            }
            if (role >= 2) {
                #pragma unroll
                for (int ks = 0; ks < 4; ++ks) {
                    const int k0 = ks * 32 + kq;
                    a4r[ks] = *(const short8*)
                        &h2sh[rb][fr * 128 + (k0 ^ ((fr & 7) << 3))];
                }
            }
            const int sec = (role == 1) ? 0 : (role == 2) ? 256 : 768;
            const int Hl  = (role == 2) ? 128 : 64;
            #pragma unroll
            for (int ut = 0; ut < 2; ++ut)
                #pragma unroll
                for (int g = 0; g < 4; ++g) {
                    f32x4 acc = {};
                    #pragma unroll
                    for (int ks = 0; ks < 2; ++ks)
                        acc = __builtin_amdgcn_mfma_f32_16x16x32_bf16(
                            a2r[ks], bregB[ut][g][ks], acc, 0, 0, 0);
                    if (role >= 2) {
                        #pragma unroll
                        for (int ks = 0; ks < 4; ++ks)
                            acc = __builtin_amdgcn_mfma_f32_16x16x32_bf16(
                                a4r[ks], bregA[ut][g][ks], acc, 0, 0, 0);
                    }
                    if (hi == 0) {      // rows 0-3 are the real batch rows
                        const int col = sec + g * Hl + uw + ut * 16 + fr;
                        #pragma unroll
                        for (int j = 0; j < 4; ++j)
                            gsh[j][col] = acc[j];
                    }
                }
        }
        __syncthreads();                 // gates visible

        #pragma unroll
        for (int i = 0; i < 2; ++i) {
            const int item = tid + i * 512;
            const int row = item >> 8, ug = item & 255;
            int u, Hl, sec, tt, lay;
            if (ug < 64)       { lay = 1; u = ug;       Hl = 64;  sec = 0;   tt = s; }
            else if (ug < 192) { lay = 2; u = ug - 64;  Hl = 128; sec = 256; tt = s - 1; }
            else               { lay = 3; u = ug - 192; Hl = 64;  sec = 768; tt = s - 2; }
            if (tt >= 0 && tt < Tn) {
                const int col0 = sec + u;
                float gi = gsh[row][col0]          + bsh[col0];
                float gf = gsh[row][col0 + Hl]     + bsh[col0 + Hl];
                float gg = gsh[row][col0 + 2 * Hl] + bsh[col0 + 2 * Hl];
                float go = gsh[row][col0 + 3 * Hl] + bsh[col0 + 3 * Hl];
                if (lay == 1) {
                    const ushort_t* xb = &xsh[s & 1][row * 256 + u];
                    gi += bf2f(xb[0]);   gf += bf2f(xb[64]);
                    gg += bf2f(xb[128]); go += bf2f(xb[192]);
                }
                const float iv = sigmoid_f(gi);
                const float fv = sigmoid_f(gf);
                const float gv = tanh_f(gg);
                const float ov = sigmoid_f(go);
                c[i] = fmaf(fv, c[i], iv * gv);
                const float h = ov * tanh_f(c[i]);
                ushort_t* hdst = (lay == 1) ? h1sh[wb]
                               : (lay == 2) ? h2sh[wb] : h3sh[wb];
                hdst[row * Hl + (u ^ (row << 3))] = f2bf(h);   // row<4
                if (lay == 3 && tt == Tn - 1)
                    hlast[(size_t)(r0 + row) * 64 + u] = h;
            }
        }

        if (doX) {
            const int rw = tid >> 5, xc = (tid & 31) * 8;
            *(short8*)&xsh[(s + 1) & 1][rw * 256 + xc] = xr;
        }
        __syncthreads();                 // h(wb), xg(s+1) visible
    }
}

// ---------------------------------------------------------------------------
// FC head: hlast[B,64] -> fc1 relu -> fc2 relu -> fc3 -> softmax
// ---------------------------------------------------------------------------
__global__ __launch_bounds__(256) void head_kernel(
    const float* __restrict__ hlast,
    const float* __restrict__ w1, const float* __restrict__ b1,
    const float* __restrict__ w2, const float* __restrict__ b2,
    const float* __restrict__ w3, const float* __restrict__ b3,
    float* __restrict__ out)
{
    __shared__ float W1[64][64];
    __shared__ float W2[32][64];
    __shared__ float W3[3][32];
    __shared__ float hin[16][64];
    __shared__ float a1[16][64];
    __shared__ float a2[16][32];
    __shared__ float lg[16][3];

    const int tid = threadIdx.x;
    const int r0 = blockIdx.x * 16;

    for (int i = tid; i < 64 * 64; i += 256) W1[i >> 6][i & 63] = w1[i];
    for (int i = tid; i < 32 * 64; i += 256) W2[i >> 6][i & 63] = w2[i];
    for (int i = tid; i < 3 * 32; i += 256) W3[i >> 5][i & 31] = w3[i];
    for (int i = tid; i < 16 * 64; i += 256) {
        int r = i >> 6, u = i & 63;
        hin[r][u] = hlast[(size_t)(r0 + r) * 64 + u];
    }
    __syncthreads();

    for (int i = tid; i < 16 * 64; i += 256) {
        int r = i >> 6, j = i & 63;
        float s = b1[j];
        #pragma unroll
        for (int k = 0; k < 64; ++k) s = fmaf(hin[r][k], W1[j][k], s);
        a1[r][j] = fmaxf(s, 0.f);
    }
    __syncthreads();

    for (int i = tid; i < 16 * 32; i += 256) {
        int r = i >> 5, j = i & 31;
        float s = b2[j];
        #pragma unroll
        for (int k = 0; k < 64; ++k) s = fmaf(a1[r][k], W2[j][k], s);
        a2[r][j] = fmaxf(s, 0.f);
    }
    __syncthreads();

    for (int i = tid; i < 16 * 3; i += 256) {
        int r = i / 3, j = i % 3;
        float s = b3[j];
        #pragma unroll
        for (int k = 0; k < 32; ++k) s = fmaf(a2[r][k], W3[j][k], s);
        lg[r][j] = s;
    }
    __syncthreads();

    if (tid < 16) {
        float l0 = lg[tid][0], l1 = lg[tid][1], l2 = lg[tid][2];
        float m = fmaxf(l0, fmaxf(l1, l2));
        float e0 = __expf(l0 - m), e1 = __expf(l1 - m), e2 = __expf(l2 - m);
        float inv = 1.0f / (e0 + e1 + e2);
        out[(size_t)(r0 + tid) * 3 + 0] = e0 * inv;
        out[(size_t)(r0 + tid) * 3 + 1] = e1 * inv;
        out[(size_t)(r0 + tid) * 3 + 2] = e2 * inv;
    }
}

// ---------------------------------------------------------------------------
extern "C" void kernel_launch(void* const* d_in, const int* in_sizes, int n_in,
                              void* d_out, int out_size, void* d_ws, size_t ws_size,
                              hipStream_t stream)
{
    const float* x    = (const float*)d_in[0];
    const float* wih1 = (const float*)d_in[1];
    const float* whh1 = (const float*)d_in[2];
    const float* bih1 = (const float*)d_in[3];
    const float* bhh1 = (const float*)d_in[4];
    const float* wih2 = (const float*)d_in[5];
    const float* whh2 = (const float*)d_in[6];
    const float* bih2 = (const float*)d_in[7];
    const float* bhh2 = (const float*)d_in[8];
    const float* wih3 = (const float*)d_in[9];
    const float* whh3 = (const float*)d_in[10];
    const float* bih3 = (const float*)d_in[11];
    const float* bhh3 = (const float*)d_in[12];
    const float* f1w  = (const float*)d_in[13];
    const float* f1b  = (const float*)d_in[14];
    const float* f2w  = (const float*)d_in[15];
    const float* f2b  = (const float*)d_in[16];
    const float* f3w  = (const float*)d_in[17];
    const float* f3b  = (const float*)d_in[18];
    float* outp = (float*)d_out;

    // workspace layout (~35 MB):
    //   bufA : 33,554,432 B  (bf16 [M,256]: xg1)
    //   hlast:    262,144 B  (fp32 [B,64])
    //   w1b  : bf16 w_ih1 (~0.9 MB)
    char* wsb = (char*)d_ws;
    size_t off = 0;
    ushort_t* bufA  = (ushort_t*)(wsb + off); off += 33554432;
    float*    hlast = (float*)(wsb + off);    off += 262144;
    ushort_t* w1b   = (ushort_t*)(wsb + off);

    const int T = T_SZ;

    convert_w1<<<208, 256, 0, stream>>>(wih1, w1b);

    // Layer 1 input GEMM (simple r9 structure; 4 blocks/CU)
    gemm_l1<<<M_SZ / 64, 256, 0, stream>>>(x, w1b, bufA);

    // All three LSTM layers, pipelined, one dispatch (256 blocks = all CUs)
    lstm3_pipe<<<B_SZ / 4, 512, 0, stream>>>(
        bufA, whh1, bih1, bhh1,
        wih2, whh2, bih2, bhh2,
        wih3, whh3, bih3, bhh3,
        hlast, T);

    // Head
    head_kernel<<<B_SZ / 16, 256, 0, stream>>>(
        hlast, f1w, f1b, f2w, f2b, f3w, f3b, outp);
}